// Round 9
// baseline (622.209 us; speedup 1.0000x reference)
//
#include <hip/hip_runtime.h>
#include <stdint.h>

// RBM CD-4, fused single kernel. R9: 1024 blocks x 16 rows (8 low rows bt8..bt8+7
// paired with bt8+8192..+7) -> 4 blocks/CU, 8 waves/SIMD (R8 was 2 blocks/CU,
// occupancy-starved at 40%). Pair rows (r, r+8) sit in lanes l15 / l15+8 and share
// one 32-bit counter hash (lo16/hi16).
// h-pass: j split 8 ways (16 j/wave), 2 MFMA chains via acc[kk]; direct WH loads.
// x-pass: d split 8 ways (512 d/wave), direct WX2 loads; no in-loop barriers anywhere.
// RNG: lowbias32 counter hash; sample via fma(h,q,h) < 65536.
// ws: [WH 1MB][WX2 1MB][S 2 doubles]

#define BB 16384
#define DD 4096
#define HH 128

typedef float f32x4 __attribute__((ext_vector_type(4)));
typedef short s16x8 __attribute__((ext_vector_type(8)));

struct RbmKeys { uint32_t kh[4]; uint32_t kx[4]; };

// host-only: threefry for key derivation
static void tf2x32_host(uint32_t k0, uint32_t k1, uint32_t x0, uint32_t x1,
                        uint32_t& o0, uint32_t& o1) {
  uint32_t ks2 = k0 ^ k1 ^ 0x1BD11BDAu;
  x0 += k0; x1 += k1;
#define TFR(r) { x0 += x1; x1 = (x1 << (r)) | (x1 >> (32 - (r))); x1 ^= x0; }
  TFR(13) TFR(15) TFR(26) TFR(6)
  x0 += k1; x1 += ks2 + 1u;
  TFR(17) TFR(29) TFR(16) TFR(24)
  x0 += ks2; x1 += k0 + 2u;
  TFR(13) TFR(15) TFR(26) TFR(6)
  x0 += k0; x1 += k1 + 3u;
  TFR(17) TFR(29) TFR(16) TFR(24)
  x0 += k1; x1 += ks2 + 4u;
  TFR(13) TFR(15) TFR(26) TFR(6)
  x0 += ks2; x1 += k0 + 5u;
#undef TFR
  o0 = x0; o1 = x1;
}

__device__ __forceinline__ uint32_t mix32(uint32_t x) {   // lowbias32
  x ^= x >> 16; x *= 0x21f0aaadu;
  x ^= x >> 15; x *= 0x735a2d97u;
  x ^= x >> 15;
  return x;
}

// sample: u16 < 65536*sigm(z)  <=>  fma(h, 2^(-z*log2e), h) < 65536
__device__ __forceinline__ bool samp16(uint32_t h16, float z) {
  float q = __builtin_amdgcn_exp2f(-1.442695041f * z);
  float hf = (float)h16;
  return fmaf(hf, q, hf) < 65536.0f;
}
__device__ __forceinline__ float softplusf(float z) {
  float e = __builtin_amdgcn_exp2f(-1.442695041f * fabsf(z));
  return fmaxf(z, 0.0f) + log1pf(e);
}

// byte (8 bits) -> 8 packed bf16 {0,1}
__device__ __forceinline__ s16x8 expand8(uint32_t byte) {
  uint32_t n0 = byte & 0xFu, n1 = byte >> 4;
  union { s16x8 v; uint32_t u[4]; } r;
  r.u[0] = ((n0 * 0x40008001u) & 0x00010001u) * 0x3F80u;
  r.u[1] = (((n0 >> 2) * 0x40008001u) & 0x00010001u) * 0x3F80u;
  r.u[2] = ((n1 * 0x40008001u) & 0x00010001u) * 0x3F80u;
  r.u[3] = (((n1 >> 2) * 0x40008001u) & 0x00010001u) * 0x3F80u;
  return r.v;
}

// ---- W fp32 [D][H] -> WH  (h-image:  granule g=(d>>3)*128+j holds W[d&~7 .. +8][j])
//                    -> WX2 (x-image: [dt=d>>4][jg=j>>3][dl=d&15][je=j&7], 16B/lane) ----
__global__ __launch_bounds__(512) void k_prep(const float* __restrict__ W,
                                              unsigned short* __restrict__ WH,
                                              unsigned short* __restrict__ WX2) {
  unsigned idx = blockIdx.x * 512u + threadIdx.x;   // over D*H
  uint32_t u = __float_as_uint(W[idx]);
  unsigned short r = (unsigned short)((u + 0x7FFFu + ((u >> 16) & 1u)) >> 16); // RTNE
  unsigned d = idx >> 7, j = idx & 127u;
  WH[((d >> 3) * 128u + j) * 8u + (d & 7u)] = r;
  WX2[((d >> 4) * 16u + (j >> 3)) * 128u + (d & 15u) * 8u + (j & 7u)] = r;
}

__global__ __launch_bounds__(512, 8) void k_rbm(const float* __restrict__ x,
                                                const unsigned short* __restrict__ WH,
                                                const unsigned short* __restrict__ WX2,
                                                const float* __restrict__ bx,
                                                const float* __restrict__ bh,
                                                double* __restrict__ S,
                                                RbmKeys K) {
  __shared__ uint32_t xbits[16 * 132];     // 8.4 KB: 16 rows x 128 words (+4 pad)
  __shared__ unsigned short hb16[16 * 8];  // 256 B: 16 rows x 128 h-bits
  __shared__ double sred[8];

  const int t = threadIdx.x;
  const int l = t & 63;
  const int w = t >> 6;
  const int rs = l >> 4;
  const int l15 = l & 15;
  const unsigned bt8 = blockIdx.x * 8u;   // rows: r<8 -> bt8+r ; r>=8 -> 8192+bt8+(r-8)

  // wave w owns j-range [w*16, w*16+16) in the h-pass
  float bhv[4];
#pragma unroll
  for (int reg = 0; reg < 4; ++reg) bhv[reg] = bh[w * 16 + rs * 4 + reg];

  // ---------- P0: load x rows, pack bits, accumulate x.bx ----------
  {
    float vbx = 0.f;
#pragma unroll 1
    for (int q = 0; q < 2; ++q) {
      const int lr = w * 2 + q;
      const unsigned g = bt8 + (unsigned)(lr & 7) + (unsigned)((lr >> 3) << 13);
      const f32x4* xrow = (const f32x4*)(x + (size_t)g * DD);
#pragma unroll
      for (int it = 0; it < 16; ++it) {
        f32x4 v = xrow[it * 64 + l];
        f32x4 bv = *(const f32x4*)(bx + it * 256 + l * 4);
        vbx += v.x * bv.x + v.y * bv.y + v.z * bv.z + v.w * bv.w;
        uint32_t nib = (v.x != 0.f ? 1u : 0u) | (v.y != 0.f ? 2u : 0u) |
                       (v.z != 0.f ? 4u : 0u) | (v.w != 0.f ? 8u : 0u);
        uint32_t word = nib << (4 * (l & 7));
        word |= __shfl_xor(word, 1);
        word |= __shfl_xor(word, 2);
        word |= __shfl_xor(word, 4);
        if ((l & 7) == 0) xbits[lr * 132 + it * 8 + (l >> 3)] = word;
      }
    }
#pragma unroll
    for (int off = 32; off; off >>= 1) vbx += __shfl_xor(vbx, off);
    if (l == 0) sred[w] = (double)vbx;
    __syncthreads();
    if (t == 0) {
      double s = 0.0;
      for (int i = 0; i < 8; ++i) s += sred[i];
      atomicAdd(S + 0, s);
    }
  }

#pragma unroll 1
  for (int step = 0; step < 5; ++step) {
    // ========== h-pass: C^T[j][b], K=4096, direct WH loads, 2 acc chains ==========
    __syncthreads();   // previous x-pass xbits writes visible
    f32x4 acc0 = (f32x4){0.f, 0.f, 0.f, 0.f};
    f32x4 acc1 = (f32x4){0.f, 0.f, 0.f, 0.f};
#pragma unroll 2
    for (int c = 0; c < 64; ++c) {
      uint32_t w0 = xbits[l15 * 132 + c * 2];
      uint32_t w1 = xbits[l15 * 132 + c * 2 + 1];
      s16x8 bf0 = expand8((w0 >> (8 * rs)) & 0xffu);
      const s16x8 af0 = *(const s16x8*)(WH +
          ((unsigned)(c * 8 + rs) * 128u + (unsigned)(w * 16 + l15)) * 8u);
      acc0 = __builtin_amdgcn_mfma_f32_16x16x32_bf16(af0, bf0, acc0, 0, 0, 0);
      s16x8 bf1 = expand8((w1 >> (8 * rs)) & 0xffu);
      const s16x8 af1 = *(const s16x8*)(WH +
          ((unsigned)(c * 8 + 4 + rs) * 128u + (unsigned)(w * 16 + l15)) * 8u);
      acc1 = __builtin_amdgcn_mfma_f32_16x16x32_bf16(af1, bf1, acc1, 0, 0, 0);
    }
    f32x4 acc;
#pragma unroll
    for (int reg = 0; reg < 4; ++reg) acc[reg] = acc0[reg] + acc1[reg];

    // ---------- h epilogue: sample h (steps 0-3) / energy (steps 0,4) ----------
    if (step < 4) {
      const uint32_t key = K.kh[step];
      const unsigned glow = bt8 + (unsigned)(l15 & 7);
      uint32_t mask = 0;
      float loc = 0.f;
#pragma unroll
      for (int reg = 0; reg < 4; ++reg) {
        const int jj = w * 16 + rs * 4 + reg;
        float z = acc[reg] + bhv[reg];
        if (step == 0) loc += softplusf(z);
        uint32_t h32 = mix32((glow * 128u + (unsigned)jj) ^ key);
        uint32_t h16 = (l15 >= 8) ? (h32 >> 16) : (h32 & 0xffffu);
        mask |= (samp16(h16, z) ? 1u : 0u) << (rs * 4 + reg);
      }
      mask |= __shfl_xor(mask, 16);
      mask |= __shfl_xor(mask, 32);
      if (rs == 0) hb16[l15 * 8 + w] = (unsigned short)mask;
      if (step == 0) {
#pragma unroll
        for (int off = 32; off; off >>= 1) loc += __shfl_xor(loc, off);
        if (l == 0) sred[w] = (double)loc;
      }
      __syncthreads();   // hb16 (and sred) visible
      if (step == 0 && t == 0) {
        double s = 0.0;
        for (int i = 0; i < 8; ++i) s += sred[i];
        atomicAdd(S + 0, s);
      }
    } else {
      float loc = 0.f;
#pragma unroll
      for (int reg = 0; reg < 4; ++reg)
        loc += softplusf(acc[reg] + bhv[reg]);
#pragma unroll
      for (int off = 32; off; off >>= 1) loc += __shfl_xor(loc, off);
      if (l == 0) sred[w] = (double)loc;
      __syncthreads();
      if (t == 0) {
        double s = 0.0;
        for (int i = 0; i < 8; ++i) s += sred[i];
        atomicAdd(S + 1, s);
      }
    }

    // ================= x-pass: K=128, barrier-free, direct WX2 loads =================
    if (step < 4) {
      const uint32_t key = K.kx[step];
      const uint32_t* hb32 = (const uint32_t*)hb16;
      s16x8 bfr[4];   // h B-fragments (16 rows), hoisted for whole pass
#pragma unroll
      for (int ch = 0; ch < 4; ++ch) {
        uint32_t hw = hb32[l15 * 4 + ch];
        bfr[ch] = expand8((hw >> (8 * rs)) & 0xffu);
      }
      float vbx1 = 0.f;
      const unsigned mrow = (bt8 + (unsigned)(l15 & 7)) * 4096u;
      const bool hi = (l15 >= 8);
#pragma unroll 1
      for (int dsub = 0; dsub < 16; ++dsub) {
        const int dbase = w * 512 + dsub * 32;
        s16x8 af[2][4];
#pragma unroll
        for (int rg = 0; rg < 2; ++rg) {
          const unsigned dt = (unsigned)(w * 32 + dsub * 2 + rg);
#pragma unroll
          for (int ch = 0; ch < 4; ++ch)
            af[rg][ch] = *(const s16x8*)(WX2 + dt * 2048u +
                                         (unsigned)(ch * 4 + rs) * 128u + (unsigned)l15 * 8u);
        }
        f32x4 acc2[2];
        acc2[0] = (f32x4){0.f,0.f,0.f,0.f};
        acc2[1] = (f32x4){0.f,0.f,0.f,0.f};
#pragma unroll
        for (int ch = 0; ch < 4; ++ch)
#pragma unroll
          for (int rg = 0; rg < 2; ++rg)
            acc2[rg] = __builtin_amdgcn_mfma_f32_16x16x32_bf16(af[rg][ch], bfr[ch],
                                                               acc2[rg], 0, 0, 0);
        uint32_t mm = 0;
#pragma unroll
        for (int rg = 0; rg < 2; ++rg) {
          f32x4 bx4 = *(const f32x4*)(bx + dbase + rg * 16 + rs * 4);
#pragma unroll
          for (int reg = 0; reg < 4; ++reg) {
            const int pos = rg * 16 + rs * 4 + reg;
            const unsigned d = (unsigned)(dbase + pos);
            uint32_t h32 = mix32((mrow + d) ^ key);
            uint32_t h16 = hi ? (h32 >> 16) : (h32 & 0xffffu);
            float z = acc2[rg][reg] + bx4[reg];
            bool s = samp16(h16, z);
            mm |= (s ? 1u : 0u) << pos;
            if (step == 3 && s) vbx1 += bx4[reg];
          }
        }
        mm |= __shfl_xor(mm, 16);
        mm |= __shfl_xor(mm, 32);
        if (rs == 0) xbits[l15 * 132 + w * 16 + dsub] = mm;
      }
      if (step == 3) {
#pragma unroll
        for (int off = 32; off; off >>= 1) vbx1 += __shfl_xor(vbx1, off);
        if (l == 0) sred[w] = (double)vbx1;
        __syncthreads();
        if (t == 0) {
          double s = 0.0;
          for (int i = 0; i < 8; ++i) s += sred[i];
          atomicAdd(S + 1, s);
        }
      }
      // next h-pass begins with __syncthreads(), ordering these xbits writes
    }
  }
}

__global__ void k_final(const double* __restrict__ S, float* __restrict__ out) {
  if (threadIdx.x == 0 && blockIdx.x == 0)
    out[0] = (float)((S[1] - S[0]) / (double)BB);   // mean F(x) - mean F(x_rec)
}

extern "C" void kernel_launch(void* const* d_in, const int* in_sizes, int n_in,
                              void* d_out, int out_size, void* d_ws, size_t ws_size,
                              hipStream_t stream) {
  const float* x  = (const float*)d_in[0];
  const float* W  = (const float*)d_in[1];
  const float* bx = (const float*)d_in[2];
  const float* bh = (const float*)d_in[3];

  const size_t IMG = (size_t)DD * HH * 2;   // 1 MB each
  if (ws_size < 2 * IMG + 64) return;

  unsigned short* WH  = (unsigned short*)d_ws;
  unsigned short* WX2 = (unsigned short*)((char*)d_ws + IMG);
  double* S = (double*)((char*)d_ws + 2 * IMG);

  hipMemsetAsync(S, 0, 2 * sizeof(double), stream);

  RbmKeys K;
  for (int i = 0; i < 4; ++i) {
    uint32_t a, b;
    tf2x32_host(0u, 42u, 0u, (uint32_t)(2 * i), a, b);
    K.kh[i] = a ^ (b * 0x9E3779B9u);
    tf2x32_host(0u, 42u, 0u, (uint32_t)(2 * i + 1), a, b);
    K.kx[i] = a ^ (b * 0x9E3779B9u);
  }

  k_prep<<<(DD * HH) / 512, 512, 0, stream>>>(W, WH, WX2);
  k_rbm<<<BB / 16, 512, 0, stream>>>(x, WH, WX2, bx, bh, S, K);
  k_final<<<1, 64, 0, stream>>>(S, (float*)d_out);
}

// Round 10
// 607.689 us; speedup vs baseline: 1.0239x; 1.0239x over previous
//
#include <hip/hip_runtime.h>
#include <stdint.h>

// RBM CD-4, fused single kernel. R10: identical to R9 except __launch_bounds__(512,6).
// R9's (512,8) imposed a 64-reg unified cap -> allocator split arch/acc ~32/32 and
// SPILLED (VGPR=32, WRITE 280MB). Cap ~85 (6 waves/EU) fits the ~75-reg working set:
// 24-28 waves/CU occupancy without scratch traffic.
// 1024 blocks x 16 rows (8 low rows bt8..bt8+7 paired with bt8+8192..+7; pair rows
// (r, r+8) sit in lanes l15/l15+8 and share one 32-bit counter hash lo16/hi16).
// h-pass: j split 8 ways (16 j/wave), 2 MFMA chains; direct WH loads (W is L2-resident).
// x-pass: d split 8 ways (512 d/wave), direct WX2 loads; no in-loop barriers anywhere.
// RNG: lowbias32 counter hash; sample via fma(h,q,h) < 65536.
// ws: [WH 1MB][WX2 1MB][S 2 doubles]

#define BB 16384
#define DD 4096
#define HH 128

typedef float f32x4 __attribute__((ext_vector_type(4)));
typedef short s16x8 __attribute__((ext_vector_type(8)));

struct RbmKeys { uint32_t kh[4]; uint32_t kx[4]; };

// host-only: threefry for key derivation
static void tf2x32_host(uint32_t k0, uint32_t k1, uint32_t x0, uint32_t x1,
                        uint32_t& o0, uint32_t& o1) {
  uint32_t ks2 = k0 ^ k1 ^ 0x1BD11BDAu;
  x0 += k0; x1 += k1;
#define TFR(r) { x0 += x1; x1 = (x1 << (r)) | (x1 >> (32 - (r))); x1 ^= x0; }
  TFR(13) TFR(15) TFR(26) TFR(6)
  x0 += k1; x1 += ks2 + 1u;
  TFR(17) TFR(29) TFR(16) TFR(24)
  x0 += ks2; x1 += k0 + 2u;
  TFR(13) TFR(15) TFR(26) TFR(6)
  x0 += k0; x1 += k1 + 3u;
  TFR(17) TFR(29) TFR(16) TFR(24)
  x0 += k1; x1 += ks2 + 4u;
  TFR(13) TFR(15) TFR(26) TFR(6)
  x0 += ks2; x1 += k0 + 5u;
#undef TFR
  o0 = x0; o1 = x1;
}

__device__ __forceinline__ uint32_t mix32(uint32_t x) {   // lowbias32
  x ^= x >> 16; x *= 0x21f0aaadu;
  x ^= x >> 15; x *= 0x735a2d97u;
  x ^= x >> 15;
  return x;
}

// sample: u16 < 65536*sigm(z)  <=>  fma(h, 2^(-z*log2e), h) < 65536
__device__ __forceinline__ bool samp16(uint32_t h16, float z) {
  float q = __builtin_amdgcn_exp2f(-1.442695041f * z);
  float hf = (float)h16;
  return fmaf(hf, q, hf) < 65536.0f;
}
__device__ __forceinline__ float softplusf(float z) {
  float e = __builtin_amdgcn_exp2f(-1.442695041f * fabsf(z));
  return fmaxf(z, 0.0f) + log1pf(e);
}

// byte (8 bits) -> 8 packed bf16 {0,1}
__device__ __forceinline__ s16x8 expand8(uint32_t byte) {
  uint32_t n0 = byte & 0xFu, n1 = byte >> 4;
  union { s16x8 v; uint32_t u[4]; } r;
  r.u[0] = ((n0 * 0x40008001u) & 0x00010001u) * 0x3F80u;
  r.u[1] = (((n0 >> 2) * 0x40008001u) & 0x00010001u) * 0x3F80u;
  r.u[2] = ((n1 * 0x40008001u) & 0x00010001u) * 0x3F80u;
  r.u[3] = (((n1 >> 2) * 0x40008001u) & 0x00010001u) * 0x3F80u;
  return r.v;
}

// ---- W fp32 [D][H] -> WH  (h-image:  granule g=(d>>3)*128+j holds W[d&~7 .. +8][j])
//                    -> WX2 (x-image: [dt=d>>4][jg=j>>3][dl=d&15][je=j&7], 16B/lane) ----
__global__ __launch_bounds__(512) void k_prep(const float* __restrict__ W,
                                              unsigned short* __restrict__ WH,
                                              unsigned short* __restrict__ WX2) {
  unsigned idx = blockIdx.x * 512u + threadIdx.x;   // over D*H
  uint32_t u = __float_as_uint(W[idx]);
  unsigned short r = (unsigned short)((u + 0x7FFFu + ((u >> 16) & 1u)) >> 16); // RTNE
  unsigned d = idx >> 7, j = idx & 127u;
  WH[((d >> 3) * 128u + j) * 8u + (d & 7u)] = r;
  WX2[((d >> 4) * 16u + (j >> 3)) * 128u + (d & 15u) * 8u + (j & 7u)] = r;
}

__global__ __launch_bounds__(512, 6) void k_rbm(const float* __restrict__ x,
                                                const unsigned short* __restrict__ WH,
                                                const unsigned short* __restrict__ WX2,
                                                const float* __restrict__ bx,
                                                const float* __restrict__ bh,
                                                double* __restrict__ S,
                                                RbmKeys K) {
  __shared__ uint32_t xbits[16 * 132];     // 8.4 KB: 16 rows x 128 words (+4 pad)
  __shared__ unsigned short hb16[16 * 8];  // 256 B: 16 rows x 128 h-bits
  __shared__ double sred[8];

  const int t = threadIdx.x;
  const int l = t & 63;
  const int w = t >> 6;
  const int rs = l >> 4;
  const int l15 = l & 15;
  const unsigned bt8 = blockIdx.x * 8u;   // rows: r<8 -> bt8+r ; r>=8 -> 8192+bt8+(r-8)

  // wave w owns j-range [w*16, w*16+16) in the h-pass
  float bhv[4];
#pragma unroll
  for (int reg = 0; reg < 4; ++reg) bhv[reg] = bh[w * 16 + rs * 4 + reg];

  // ---------- P0: load x rows, pack bits, accumulate x.bx ----------
  {
    float vbx = 0.f;
#pragma unroll 1
    for (int q = 0; q < 2; ++q) {
      const int lr = w * 2 + q;
      const unsigned g = bt8 + (unsigned)(lr & 7) + (unsigned)((lr >> 3) << 13);
      const f32x4* xrow = (const f32x4*)(x + (size_t)g * DD);
#pragma unroll
      for (int it = 0; it < 16; ++it) {
        f32x4 v = xrow[it * 64 + l];
        f32x4 bv = *(const f32x4*)(bx + it * 256 + l * 4);
        vbx += v.x * bv.x + v.y * bv.y + v.z * bv.z + v.w * bv.w;
        uint32_t nib = (v.x != 0.f ? 1u : 0u) | (v.y != 0.f ? 2u : 0u) |
                       (v.z != 0.f ? 4u : 0u) | (v.w != 0.f ? 8u : 0u);
        uint32_t word = nib << (4 * (l & 7));
        word |= __shfl_xor(word, 1);
        word |= __shfl_xor(word, 2);
        word |= __shfl_xor(word, 4);
        if ((l & 7) == 0) xbits[lr * 132 + it * 8 + (l >> 3)] = word;
      }
    }
#pragma unroll
    for (int off = 32; off; off >>= 1) vbx += __shfl_xor(vbx, off);
    if (l == 0) sred[w] = (double)vbx;
    __syncthreads();
    if (t == 0) {
      double s = 0.0;
      for (int i = 0; i < 8; ++i) s += sred[i];
      atomicAdd(S + 0, s);
    }
  }

#pragma unroll 1
  for (int step = 0; step < 5; ++step) {
    // ========== h-pass: C^T[j][b], K=4096, direct WH loads, 2 acc chains ==========
    __syncthreads();   // previous x-pass xbits writes visible
    f32x4 acc0 = (f32x4){0.f, 0.f, 0.f, 0.f};
    f32x4 acc1 = (f32x4){0.f, 0.f, 0.f, 0.f};
#pragma unroll 2
    for (int c = 0; c < 64; ++c) {
      uint32_t w0 = xbits[l15 * 132 + c * 2];
      uint32_t w1 = xbits[l15 * 132 + c * 2 + 1];
      s16x8 bf0 = expand8((w0 >> (8 * rs)) & 0xffu);
      const s16x8 af0 = *(const s16x8*)(WH +
          ((unsigned)(c * 8 + rs) * 128u + (unsigned)(w * 16 + l15)) * 8u);
      acc0 = __builtin_amdgcn_mfma_f32_16x16x32_bf16(af0, bf0, acc0, 0, 0, 0);
      s16x8 bf1 = expand8((w1 >> (8 * rs)) & 0xffu);
      const s16x8 af1 = *(const s16x8*)(WH +
          ((unsigned)(c * 8 + 4 + rs) * 128u + (unsigned)(w * 16 + l15)) * 8u);
      acc1 = __builtin_amdgcn_mfma_f32_16x16x32_bf16(af1, bf1, acc1, 0, 0, 0);
    }
    f32x4 acc;
#pragma unroll
    for (int reg = 0; reg < 4; ++reg) acc[reg] = acc0[reg] + acc1[reg];

    // ---------- h epilogue: sample h (steps 0-3) / energy (steps 0,4) ----------
    if (step < 4) {
      const uint32_t key = K.kh[step];
      const unsigned glow = bt8 + (unsigned)(l15 & 7);
      uint32_t mask = 0;
      float loc = 0.f;
#pragma unroll
      for (int reg = 0; reg < 4; ++reg) {
        const int jj = w * 16 + rs * 4 + reg;
        float z = acc[reg] + bhv[reg];
        if (step == 0) loc += softplusf(z);
        uint32_t h32 = mix32((glow * 128u + (unsigned)jj) ^ key);
        uint32_t h16 = (l15 >= 8) ? (h32 >> 16) : (h32 & 0xffffu);
        mask |= (samp16(h16, z) ? 1u : 0u) << (rs * 4 + reg);
      }
      mask |= __shfl_xor(mask, 16);
      mask |= __shfl_xor(mask, 32);
      if (rs == 0) hb16[l15 * 8 + w] = (unsigned short)mask;
      if (step == 0) {
#pragma unroll
        for (int off = 32; off; off >>= 1) loc += __shfl_xor(loc, off);
        if (l == 0) sred[w] = (double)loc;
      }
      __syncthreads();   // hb16 (and sred) visible
      if (step == 0 && t == 0) {
        double s = 0.0;
        for (int i = 0; i < 8; ++i) s += sred[i];
        atomicAdd(S + 0, s);
      }
    } else {
      float loc = 0.f;
#pragma unroll
      for (int reg = 0; reg < 4; ++reg)
        loc += softplusf(acc[reg] + bhv[reg]);
#pragma unroll
      for (int off = 32; off; off >>= 1) loc += __shfl_xor(loc, off);
      if (l == 0) sred[w] = (double)loc;
      __syncthreads();
      if (t == 0) {
        double s = 0.0;
        for (int i = 0; i < 8; ++i) s += sred[i];
        atomicAdd(S + 1, s);
      }
    }

    // ================= x-pass: K=128, barrier-free, direct WX2 loads =================
    if (step < 4) {
      const uint32_t key = K.kx[step];
      const uint32_t* hb32 = (const uint32_t*)hb16;
      s16x8 bfr[4];   // h B-fragments (16 rows), hoisted for whole pass
#pragma unroll
      for (int ch = 0; ch < 4; ++ch) {
        uint32_t hw = hb32[l15 * 4 + ch];
        bfr[ch] = expand8((hw >> (8 * rs)) & 0xffu);
      }
      float vbx1 = 0.f;
      const unsigned mrow = (bt8 + (unsigned)(l15 & 7)) * 4096u;
      const bool hi = (l15 >= 8);
#pragma unroll 1
      for (int dsub = 0; dsub < 16; ++dsub) {
        const int dbase = w * 512 + dsub * 32;
        s16x8 af[2][4];
#pragma unroll
        for (int rg = 0; rg < 2; ++rg) {
          const unsigned dt = (unsigned)(w * 32 + dsub * 2 + rg);
#pragma unroll
          for (int ch = 0; ch < 4; ++ch)
            af[rg][ch] = *(const s16x8*)(WX2 + dt * 2048u +
                                         (unsigned)(ch * 4 + rs) * 128u + (unsigned)l15 * 8u);
        }
        f32x4 acc2[2];
        acc2[0] = (f32x4){0.f,0.f,0.f,0.f};
        acc2[1] = (f32x4){0.f,0.f,0.f,0.f};
#pragma unroll
        for (int ch = 0; ch < 4; ++ch)
#pragma unroll
          for (int rg = 0; rg < 2; ++rg)
            acc2[rg] = __builtin_amdgcn_mfma_f32_16x16x32_bf16(af[rg][ch], bfr[ch],
                                                               acc2[rg], 0, 0, 0);
        uint32_t mm = 0;
#pragma unroll
        for (int rg = 0; rg < 2; ++rg) {
          f32x4 bx4 = *(const f32x4*)(bx + dbase + rg * 16 + rs * 4);
#pragma unroll
          for (int reg = 0; reg < 4; ++reg) {
            const int pos = rg * 16 + rs * 4 + reg;
            const unsigned d = (unsigned)(dbase + pos);
            uint32_t h32 = mix32((mrow + d) ^ key);
            uint32_t h16 = hi ? (h32 >> 16) : (h32 & 0xffffu);
            float z = acc2[rg][reg] + bx4[reg];
            bool s = samp16(h16, z);
            mm |= (s ? 1u : 0u) << pos;
            if (step == 3 && s) vbx1 += bx4[reg];
          }
        }
        mm |= __shfl_xor(mm, 16);
        mm |= __shfl_xor(mm, 32);
        if (rs == 0) xbits[l15 * 132 + w * 16 + dsub] = mm;
      }
      if (step == 3) {
#pragma unroll
        for (int off = 32; off; off >>= 1) vbx1 += __shfl_xor(vbx1, off);
        if (l == 0) sred[w] = (double)vbx1;
        __syncthreads();
        if (t == 0) {
          double s = 0.0;
          for (int i = 0; i < 8; ++i) s += sred[i];
          atomicAdd(S + 1, s);
        }
      }
      // next h-pass begins with __syncthreads(), ordering these xbits writes
    }
  }
}

__global__ void k_final(const double* __restrict__ S, float* __restrict__ out) {
  if (threadIdx.x == 0 && blockIdx.x == 0)
    out[0] = (float)((S[1] - S[0]) / (double)BB);   // mean F(x) - mean F(x_rec)
}

extern "C" void kernel_launch(void* const* d_in, const int* in_sizes, int n_in,
                              void* d_out, int out_size, void* d_ws, size_t ws_size,
                              hipStream_t stream) {
  const float* x  = (const float*)d_in[0];
  const float* W  = (const float*)d_in[1];
  const float* bx = (const float*)d_in[2];
  const float* bh = (const float*)d_in[3];

  const size_t IMG = (size_t)DD * HH * 2;   // 1 MB each
  if (ws_size < 2 * IMG + 64) return;

  unsigned short* WH  = (unsigned short*)d_ws;
  unsigned short* WX2 = (unsigned short*)((char*)d_ws + IMG);
  double* S = (double*)((char*)d_ws + 2 * IMG);

  hipMemsetAsync(S, 0, 2 * sizeof(double), stream);

  RbmKeys K;
  for (int i = 0; i < 4; ++i) {
    uint32_t a, b;
    tf2x32_host(0u, 42u, 0u, (uint32_t)(2 * i), a, b);
    K.kh[i] = a ^ (b * 0x9E3779B9u);
    tf2x32_host(0u, 42u, 0u, (uint32_t)(2 * i + 1), a, b);
    K.kx[i] = a ^ (b * 0x9E3779B9u);
  }

  k_prep<<<(DD * HH) / 512, 512, 0, stream>>>(W, WH, WX2);
  k_rbm<<<BB / 16, 512, 0, stream>>>(x, WH, WX2, bx, bh, S, K);
  k_final<<<1, 64, 0, stream>>>(S, (float*)d_out);
}

// Round 11
// 518.539 us; speedup vs baseline: 1.1999x; 1.1719x over previous
//
#include <hip/hip_runtime.h>
#include <stdint.h>

// RBM CD-4, fused single kernel. R11: make the (512,6) cap actually fit by shrinking
// the register working set (R10 spilled: VGPR=40 arch + WRITE 174MB):
//  - h-pass c-loop unroll 1 (was 2): halves live A-fragments (-16 regs)
//  - x-pass: per-rg af loads + two named accumulators (was af[2][4], -16 regs)
//  - hash-share: lane pair (l15, l15^8) needs IDENTICAL 8 hashes; each lane now
//    computes 4 (its rg) and shfl_xor(.,8)s the other 4 (-4 regs, -25 VALU/dsub)
// 1024 blocks x 16 rows (8 low bt8..+7 paired with +8192; pair lanes l15/l15+8
// share each 32-bit counter hash lo16/hi16).
// h-pass: j split 8 ways; direct WH loads (W L2-resident). x-pass: d split 8 ways,
// direct WX2 loads, no in-loop barriers. RNG: lowbias32; sample fma(h,q,h)<65536.
// ws: [WH 1MB][WX2 1MB][S 2 doubles]

#define BB 16384
#define DD 4096
#define HH 128

typedef float f32x4 __attribute__((ext_vector_type(4)));
typedef short s16x8 __attribute__((ext_vector_type(8)));

struct RbmKeys { uint32_t kh[4]; uint32_t kx[4]; };

// host-only: threefry for key derivation
static void tf2x32_host(uint32_t k0, uint32_t k1, uint32_t x0, uint32_t x1,
                        uint32_t& o0, uint32_t& o1) {
  uint32_t ks2 = k0 ^ k1 ^ 0x1BD11BDAu;
  x0 += k0; x1 += k1;
#define TFR(r) { x0 += x1; x1 = (x1 << (r)) | (x1 >> (32 - (r))); x1 ^= x0; }
  TFR(13) TFR(15) TFR(26) TFR(6)
  x0 += k1; x1 += ks2 + 1u;
  TFR(17) TFR(29) TFR(16) TFR(24)
  x0 += ks2; x1 += k0 + 2u;
  TFR(13) TFR(15) TFR(26) TFR(6)
  x0 += k0; x1 += k1 + 3u;
  TFR(17) TFR(29) TFR(16) TFR(24)
  x0 += k1; x1 += ks2 + 4u;
  TFR(13) TFR(15) TFR(26) TFR(6)
  x0 += ks2; x1 += k0 + 5u;
#undef TFR
  o0 = x0; o1 = x1;
}

__device__ __forceinline__ uint32_t mix32(uint32_t x) {   // lowbias32
  x ^= x >> 16; x *= 0x21f0aaadu;
  x ^= x >> 15; x *= 0x735a2d97u;
  x ^= x >> 15;
  return x;
}

// sample: u16 < 65536*sigm(z)  <=>  fma(h, 2^(-z*log2e), h) < 65536
__device__ __forceinline__ bool samp16(uint32_t h16, float z) {
  float q = __builtin_amdgcn_exp2f(-1.442695041f * z);
  float hf = (float)h16;
  return fmaf(hf, q, hf) < 65536.0f;
}
__device__ __forceinline__ float softplusf(float z) {
  float e = __builtin_amdgcn_exp2f(-1.442695041f * fabsf(z));
  return fmaxf(z, 0.0f) + log1pf(e);
}

// byte (8 bits) -> 8 packed bf16 {0,1}
__device__ __forceinline__ s16x8 expand8(uint32_t byte) {
  uint32_t n0 = byte & 0xFu, n1 = byte >> 4;
  union { s16x8 v; uint32_t u[4]; } r;
  r.u[0] = ((n0 * 0x40008001u) & 0x00010001u) * 0x3F80u;
  r.u[1] = (((n0 >> 2) * 0x40008001u) & 0x00010001u) * 0x3F80u;
  r.u[2] = ((n1 * 0x40008001u) & 0x00010001u) * 0x3F80u;
  r.u[3] = (((n1 >> 2) * 0x40008001u) & 0x00010001u) * 0x3F80u;
  return r.v;
}

// ---- W fp32 [D][H] -> WH  (h-image:  granule g=(d>>3)*128+j holds W[d&~7 .. +8][j])
//                    -> WX2 (x-image: [dt=d>>4][jg=j>>3][dl=d&15][je=j&7], 16B/lane) ----
__global__ __launch_bounds__(512) void k_prep(const float* __restrict__ W,
                                              unsigned short* __restrict__ WH,
                                              unsigned short* __restrict__ WX2) {
  unsigned idx = blockIdx.x * 512u + threadIdx.x;   // over D*H
  uint32_t u = __float_as_uint(W[idx]);
  unsigned short r = (unsigned short)((u + 0x7FFFu + ((u >> 16) & 1u)) >> 16); // RTNE
  unsigned d = idx >> 7, j = idx & 127u;
  WH[((d >> 3) * 128u + j) * 8u + (d & 7u)] = r;
  WX2[((d >> 4) * 16u + (j >> 3)) * 128u + (d & 15u) * 8u + (j & 7u)] = r;
}

__global__ __launch_bounds__(512, 6) void k_rbm(const float* __restrict__ x,
                                                const unsigned short* __restrict__ WH,
                                                const unsigned short* __restrict__ WX2,
                                                const float* __restrict__ bx,
                                                const float* __restrict__ bh,
                                                double* __restrict__ S,
                                                RbmKeys K) {
  __shared__ uint32_t xbits[16 * 132];     // 8.4 KB: 16 rows x 128 words (+4 pad)
  __shared__ unsigned short hb16[16 * 8];  // 256 B: 16 rows x 128 h-bits
  __shared__ double sred[8];

  const int t = threadIdx.x;
  const int l = t & 63;
  const int w = t >> 6;
  const int rs = l >> 4;
  const int l15 = l & 15;
  const unsigned bt8 = blockIdx.x * 8u;   // rows: r<8 -> bt8+r ; r>=8 -> 8192+bt8+(r-8)

  // wave w owns j-range [w*16, w*16+16) in the h-pass
  float bhv[4];
#pragma unroll
  for (int reg = 0; reg < 4; ++reg) bhv[reg] = bh[w * 16 + rs * 4 + reg];

  // ---------- P0: load x rows, pack bits, accumulate x.bx ----------
  {
    float vbx = 0.f;
#pragma unroll 1
    for (int q = 0; q < 2; ++q) {
      const int lr = w * 2 + q;
      const unsigned g = bt8 + (unsigned)(lr & 7) + (unsigned)((lr >> 3) << 13);
      const f32x4* xrow = (const f32x4*)(x + (size_t)g * DD);
#pragma unroll
      for (int it = 0; it < 16; ++it) {
        f32x4 v = xrow[it * 64 + l];
        f32x4 bv = *(const f32x4*)(bx + it * 256 + l * 4);
        vbx += v.x * bv.x + v.y * bv.y + v.z * bv.z + v.w * bv.w;
        uint32_t nib = (v.x != 0.f ? 1u : 0u) | (v.y != 0.f ? 2u : 0u) |
                       (v.z != 0.f ? 4u : 0u) | (v.w != 0.f ? 8u : 0u);
        uint32_t word = nib << (4 * (l & 7));
        word |= __shfl_xor(word, 1);
        word |= __shfl_xor(word, 2);
        word |= __shfl_xor(word, 4);
        if ((l & 7) == 0) xbits[lr * 132 + it * 8 + (l >> 3)] = word;
      }
    }
#pragma unroll
    for (int off = 32; off; off >>= 1) vbx += __shfl_xor(vbx, off);
    if (l == 0) sred[w] = (double)vbx;
    __syncthreads();
    if (t == 0) {
      double s = 0.0;
      for (int i = 0; i < 8; ++i) s += sred[i];
      atomicAdd(S + 0, s);
    }
  }

#pragma unroll 1
  for (int step = 0; step < 5; ++step) {
    // ========== h-pass: C^T[j][b], K=4096, direct WH loads, 2 acc chains ==========
    __syncthreads();   // previous x-pass xbits writes visible
    f32x4 acc0 = (f32x4){0.f, 0.f, 0.f, 0.f};
    f32x4 acc1 = (f32x4){0.f, 0.f, 0.f, 0.f};
#pragma unroll 1
    for (int c = 0; c < 64; ++c) {
      uint32_t w0 = xbits[l15 * 132 + c * 2];
      uint32_t w1 = xbits[l15 * 132 + c * 2 + 1];
      s16x8 bf0 = expand8((w0 >> (8 * rs)) & 0xffu);
      const s16x8 af0 = *(const s16x8*)(WH +
          ((unsigned)(c * 8 + rs) * 128u + (unsigned)(w * 16 + l15)) * 8u);
      acc0 = __builtin_amdgcn_mfma_f32_16x16x32_bf16(af0, bf0, acc0, 0, 0, 0);
      s16x8 bf1 = expand8((w1 >> (8 * rs)) & 0xffu);
      const s16x8 af1 = *(const s16x8*)(WH +
          ((unsigned)(c * 8 + 4 + rs) * 128u + (unsigned)(w * 16 + l15)) * 8u);
      acc1 = __builtin_amdgcn_mfma_f32_16x16x32_bf16(af1, bf1, acc1, 0, 0, 0);
    }
    f32x4 acc;
#pragma unroll
    for (int reg = 0; reg < 4; ++reg) acc[reg] = acc0[reg] + acc1[reg];

    // ---------- h epilogue: sample h (steps 0-3) / energy (steps 0,4) ----------
    if (step < 4) {
      const uint32_t key = K.kh[step];
      const unsigned glow = bt8 + (unsigned)(l15 & 7);
      uint32_t mask = 0;
      float loc = 0.f;
#pragma unroll
      for (int reg = 0; reg < 4; ++reg) {
        const int jj = w * 16 + rs * 4 + reg;
        float z = acc[reg] + bhv[reg];
        if (step == 0) loc += softplusf(z);
        uint32_t h32 = mix32((glow * 128u + (unsigned)jj) ^ key);
        uint32_t h16 = (l15 >= 8) ? (h32 >> 16) : (h32 & 0xffffu);
        mask |= (samp16(h16, z) ? 1u : 0u) << (rs * 4 + reg);
      }
      mask |= __shfl_xor(mask, 16);
      mask |= __shfl_xor(mask, 32);
      if (rs == 0) hb16[l15 * 8 + w] = (unsigned short)mask;
      if (step == 0) {
#pragma unroll
        for (int off = 32; off; off >>= 1) loc += __shfl_xor(loc, off);
        if (l == 0) sred[w] = (double)loc;
      }
      __syncthreads();   // hb16 (and sred) visible
      if (step == 0 && t == 0) {
        double s = 0.0;
        for (int i = 0; i < 8; ++i) s += sred[i];
        atomicAdd(S + 0, s);
      }
    } else {
      float loc = 0.f;
#pragma unroll
      for (int reg = 0; reg < 4; ++reg)
        loc += softplusf(acc[reg] + bhv[reg]);
#pragma unroll
      for (int off = 32; off; off >>= 1) loc += __shfl_xor(loc, off);
      if (l == 0) sred[w] = (double)loc;
      __syncthreads();
      if (t == 0) {
        double s = 0.0;
        for (int i = 0; i < 8; ++i) s += sred[i];
        atomicAdd(S + 1, s);
      }
    }

    // ============ x-pass: K=128, barrier-free, per-rg WX2 loads, hash-share ============
    if (step < 4) {
      const uint32_t key = K.kx[step];
      const uint32_t* hb32 = (const uint32_t*)hb16;
      s16x8 bfr[4];   // h B-fragments (16 rows), hoisted for whole pass
#pragma unroll
      for (int ch = 0; ch < 4; ++ch) {
        uint32_t hw = hb32[l15 * 4 + ch];
        bfr[ch] = expand8((hw >> (8 * rs)) & 0xffu);
      }
      float vbx1 = 0.f;
      const unsigned mrow = (bt8 + (unsigned)(l15 & 7)) * 4096u;
      const bool hi = (l15 >= 8);
      const int myoff = hi ? 16 : 0;   // this lane computes hashes for its own rg
#pragma unroll 1
      for (int dsub = 0; dsub < 16; ++dsub) {
        const int dbase = w * 512 + dsub * 32;
        // ---- hashes: 4 own + 4 exchanged (pair lanes need identical 8 hashes) ----
        uint32_t hmy[4], hoth[4];
#pragma unroll
        for (int reg = 0; reg < 4; ++reg) {
          const unsigned d = (unsigned)(dbase + myoff + rs * 4 + reg);
          hmy[reg] = mix32((mrow + d) ^ key);
        }
#pragma unroll
        for (int reg = 0; reg < 4; ++reg) hoth[reg] = __shfl_xor(hmy[reg], 8);
        // ---- MFMA: rg sequential, one af batch live at a time ----
        f32x4 a20 = (f32x4){0.f,0.f,0.f,0.f};
        f32x4 a21 = (f32x4){0.f,0.f,0.f,0.f};
        {
          const unsigned dt = (unsigned)(w * 32 + dsub * 2);
#pragma unroll
          for (int ch = 0; ch < 4; ++ch) {
            const s16x8 afv = *(const s16x8*)(WX2 + dt * 2048u +
                (unsigned)(ch * 4 + rs) * 128u + (unsigned)l15 * 8u);
            a20 = __builtin_amdgcn_mfma_f32_16x16x32_bf16(afv, bfr[ch], a20, 0, 0, 0);
          }
        }
        {
          const unsigned dt = (unsigned)(w * 32 + dsub * 2 + 1);
#pragma unroll
          for (int ch = 0; ch < 4; ++ch) {
            const s16x8 afv = *(const s16x8*)(WX2 + dt * 2048u +
                (unsigned)(ch * 4 + rs) * 128u + (unsigned)l15 * 8u);
            a21 = __builtin_amdgcn_mfma_f32_16x16x32_bf16(afv, bfr[ch], a21, 0, 0, 0);
          }
        }
        // ---- sample 8 positions ----
        uint32_t mm = 0;
        {
          f32x4 bx4 = *(const f32x4*)(bx + dbase + rs * 4);
#pragma unroll
          for (int reg = 0; reg < 4; ++reg) {
            const uint32_t h32 = hi ? hoth[reg] : hmy[reg];       // rg0 hashes
            const uint32_t h16 = hi ? (h32 >> 16) : (h32 & 0xffffu);
            float z = a20[reg] + bx4[reg];
            bool s = samp16(h16, z);
            mm |= (s ? 1u : 0u) << (rs * 4 + reg);
            if (step == 3 && s) vbx1 += bx4[reg];
          }
        }
        {
          f32x4 bx4 = *(const f32x4*)(bx + dbase + 16 + rs * 4);
#pragma unroll
          for (int reg = 0; reg < 4; ++reg) {
            const uint32_t h32 = hi ? hmy[reg] : hoth[reg];       // rg1 hashes
            const uint32_t h16 = hi ? (h32 >> 16) : (h32 & 0xffffu);
            float z = a21[reg] + bx4[reg];
            bool s = samp16(h16, z);
            mm |= (s ? 1u : 0u) << (16 + rs * 4 + reg);
            if (step == 3 && s) vbx1 += bx4[reg];
          }
        }
        mm |= __shfl_xor(mm, 16);
        mm |= __shfl_xor(mm, 32);
        if (rs == 0) xbits[l15 * 132 + w * 16 + dsub] = mm;
      }
      if (step == 3) {
#pragma unroll
        for (int off = 32; off; off >>= 1) vbx1 += __shfl_xor(vbx1, off);
        if (l == 0) sred[w] = (double)vbx1;
        __syncthreads();
        if (t == 0) {
          double s = 0.0;
          for (int i = 0; i < 8; ++i) s += sred[i];
          atomicAdd(S + 1, s);
        }
      }
      // next h-pass begins with __syncthreads(), ordering these xbits writes
    }
  }
}

__global__ void k_final(const double* __restrict__ S, float* __restrict__ out) {
  if (threadIdx.x == 0 && blockIdx.x == 0)
    out[0] = (float)((S[1] - S[0]) / (double)BB);   // mean F(x) - mean F(x_rec)
}

extern "C" void kernel_launch(void* const* d_in, const int* in_sizes, int n_in,
                              void* d_out, int out_size, void* d_ws, size_t ws_size,
                              hipStream_t stream) {
  const float* x  = (const float*)d_in[0];
  const float* W  = (const float*)d_in[1];
  const float* bx = (const float*)d_in[2];
  const float* bh = (const float*)d_in[3];

  const size_t IMG = (size_t)DD * HH * 2;   // 1 MB each
  if (ws_size < 2 * IMG + 64) return;

  unsigned short* WH  = (unsigned short*)d_ws;
  unsigned short* WX2 = (unsigned short*)((char*)d_ws + IMG);
  double* S = (double*)((char*)d_ws + 2 * IMG);

  hipMemsetAsync(S, 0, 2 * sizeof(double), stream);

  RbmKeys K;
  for (int i = 0; i < 4; ++i) {
    uint32_t a, b;
    tf2x32_host(0u, 42u, 0u, (uint32_t)(2 * i), a, b);
    K.kh[i] = a ^ (b * 0x9E3779B9u);
    tf2x32_host(0u, 42u, 0u, (uint32_t)(2 * i + 1), a, b);
    K.kx[i] = a ^ (b * 0x9E3779B9u);
  }

  k_prep<<<(DD * HH) / 512, 512, 0, stream>>>(W, WH, WX2);
  k_rbm<<<BB / 16, 512, 0, stream>>>(x, WH, WX2, bx, bh, S, K);
  k_final<<<1, 64, 0, stream>>>(S, (float*)d_out);
}